// Round 8
// baseline (537.123 us; speedup 1.0000x reference)
//
#include <hip/hip_runtime.h>
#include <hip/hip_bf16.h>
#include <math.h>

#define N_NODES 4096
#define IN_DIM  768
#define HID     256
#define HEADS   4
#define OUT_DIM 32
#define ALPHA   0.2f
#define GCOLS   (HEADS*HID)   // 1024
#define NWORDS  (N_NODES/32)  // 128 mask words per row
#define LOG2E   1.4426950408889634f

typedef unsigned short ushort_t;
typedef short bf16x8 __attribute__((ext_vector_type(8)));
typedef float f32x4 __attribute__((ext_vector_type(4)));

__device__ __forceinline__ float elu_f(float x){ return x > 0.f ? x : expm1f(x); }

__device__ __forceinline__ float fexp2(float x){
#if __has_builtin(__builtin_amdgcn_exp2f)
    return __builtin_amdgcn_exp2f(x);
#else
    return exp2f(x);
#endif
}

// RTNE f32->bf16 via builtin cast: compiler emits (and pair-fuses) v_cvt_pk_bf16_f32.
__device__ __forceinline__ ushort_t f2bf(float x){
    __hip_bfloat16 h = __float2bfloat16(x);
    return *reinterpret_cast<ushort_t*>(&h);
}
__device__ __forceinline__ float bf2f(ushort_t h){
    return __uint_as_float(((unsigned)h) << 16);
}
__device__ __forceinline__ void gload16(const void* g, void* l){
    __builtin_amdgcn_global_load_lds((const __attribute__((address_space(1))) void*)(g),
                                     (__attribute__((address_space(3))) void*)(l), 16, 0, 0);
}

// ---------------- pack adj -> bitmask maskJ[i][jword] -----------------------
__global__ __launch_bounds__(256)
void pack_kernel(const int* __restrict__ adj, unsigned* __restrict__ maskJ)
{
    const int w    = threadIdx.x >> 6;
    const int lane = threadIdx.x & 63;
    const int i    = blockIdx.x * 4 + w;
    const int* arow = adj + (size_t)i * N_NODES;
    for (int jt = 0; jt < 64; ++jt) {
        unsigned long long b = __ballot(arow[jt*64 + lane] != 0);
        if (lane == 0) {
            maskJ[(size_t)i*NWORDS + jt*2    ] = (unsigned)b;
            maskJ[(size_t)i*NWORDS + jt*2 + 1] = (unsigned)(b >> 32);
        }
    }
}

// ---------------- fp32 -> bf16 hi/lo split ----------------------------------
__global__ __launch_bounds__(256)
void cvt_hilo(const float* __restrict__ x, ushort_t* __restrict__ hi,
              ushort_t* __restrict__ lo, int n)
{
    const int idx = (blockIdx.x*256 + threadIdx.x)*4;
    if (idx >= n) return;
    float4 v = *(const float4*)(x + idx);
    ushort4 h, l;
    h.x = f2bf(v.x); l.x = f2bf(v.x - bf2f(h.x));
    h.y = f2bf(v.y); l.y = f2bf(v.y - bf2f(h.y));
    h.z = f2bf(v.z); l.z = f2bf(v.z - bf2f(h.z));
    h.w = f2bf(v.w); l.w = f2bf(v.w - bf2f(h.w));
    *(ushort4*)(hi + idx) = h;
    *(ushort4*)(lo + idx) = l;
}

__global__ __launch_bounds__(256)
void zero_kernel(float* p, int n){
    int i = blockIdx.x*256 + threadIdx.x;
    if (i < n) p[i] = 0.f;
}

// ------------- hi/lo split-bf16 MFMA GEMM: C[M,N] = A[M,K] @ B[N,K]^T -------
// 3-term (AhBh + AhBl + AlBh), 128x128 tile, BK=32, 256 thr, 64x64 wave tiles.
// Attention epilogue (avec != 0) emits s_src/s_dst PRE-SCALED by log2(e).
__global__ __launch_bounds__(256)
void gemm_hilo(const ushort_t* __restrict__ Ahi, const ushort_t* __restrict__ Alo,
               const ushort_t* __restrict__ Bhi, const ushort_t* __restrict__ Blo,
               const float* __restrict__ bias, float* __restrict__ outF,
               ushort_t* __restrict__ outHi, ushort_t* __restrict__ outLo,
               const float* __restrict__ avec, float* __restrict__ ssrc,
               float* __restrict__ sdst, int M, int N, int K)
{
    __shared__ ushort_t sA[2][2][128*32];
    __shared__ ushort_t sB[2][2][128*32];
    const int tid  = threadIdx.x;
    const int w    = tid >> 6, lane = tid & 63;
    const int l15  = lane & 15, l4 = lane >> 4;
    const int wr   = w >> 1, wcl = w & 1;
    const int m0   = blockIdx.y * 128, n0 = blockIdx.x * 128;

    f32x4 acc[4][4];
#pragma unroll
    for (int r = 0; r < 4; ++r)
#pragma unroll
        for (int t = 0; t < 4; ++t) acc[r][t] = (f32x4){0.f,0.f,0.f,0.f};

    auto stage = [&](int buf, int k0){
#pragma unroll
        for (int s = 0; s < 2; ++s) {
            const int rr = w*32 + s*16;
            const int gr = rr + (lane >> 2);
            const int gc = k0 + (lane & 3)*8;
            gload16(Ahi + (size_t)(m0+gr)*K + gc, &sA[buf][0][rr*32]);
            gload16(Alo + (size_t)(m0+gr)*K + gc, &sA[buf][1][rr*32]);
            int br = n0 + gr; if (br >= N) br = N-1;
            gload16(Bhi + (size_t)br*K + gc, &sB[buf][0][rr*32]);
            gload16(Blo + (size_t)br*K + gc, &sB[buf][1][rr*32]);
        }
    };

    stage(0, 0);
    int buf = 0;
    for (int k0 = 0; k0 < K; k0 += 32) {
        __syncthreads();
        if (k0 + 32 < K) stage(buf^1, k0 + 32);
        bf16x8 ah[4], al[4], bh[4], bl[4];
#pragma unroll
        for (int r = 0; r < 4; ++r) {
            const int off = (wr*64 + r*16 + l15)*32 + l4*8;
            ah[r] = *(const bf16x8*)&sA[buf][0][off];
            al[r] = *(const bf16x8*)&sA[buf][1][off];
        }
#pragma unroll
        for (int t = 0; t < 4; ++t) {
            const int off = (wcl*64 + t*16 + l15)*32 + l4*8;
            bh[t] = *(const bf16x8*)&sB[buf][0][off];
            bl[t] = *(const bf16x8*)&sB[buf][1][off];
        }
#pragma unroll
        for (int r = 0; r < 4; ++r)
#pragma unroll
            for (int t = 0; t < 4; ++t) {
                acc[r][t] = __builtin_amdgcn_mfma_f32_16x16x32_bf16(ah[r], bh[t], acc[r][t], 0,0,0);
                acc[r][t] = __builtin_amdgcn_mfma_f32_16x16x32_bf16(ah[r], bl[t], acc[r][t], 0,0,0);
                acc[r][t] = __builtin_amdgcn_mfma_f32_16x16x32_bf16(al[r], bh[t], acc[r][t], 0,0,0);
            }
        buf ^= 1;
    }

    const int hdr = m0 >> 8;     // head (gT GEMM: rows are head*HID+c)
    if (avec) {
        float as[4][4], ad[4][4];
#pragma unroll
        for (int r = 0; r < 4; ++r)
#pragma unroll
            for (int g = 0; g < 4; ++g) {
                const int aid = (m0 + wr*64 + r*16 + l4*4 + g) & (HID-1);
                as[r][g] = avec[hdr*2*HID + aid];
                ad[r][g] = avec[hdr*2*HID + HID + aid];
            }
#pragma unroll
        for (int t = 0; t < 4; ++t) {
            float ps = 0.f, pd = 0.f;
#pragma unroll
            for (int r = 0; r < 4; ++r)
#pragma unroll
                for (int g = 0; g < 4; ++g) {
                    ps += acc[r][t][g] * as[r][g];
                    pd += acc[r][t][g] * ad[r][g];
                }
            ps += __shfl_xor(ps, 16); ps += __shfl_xor(ps, 32);
            pd += __shfl_xor(pd, 16); pd += __shfl_xor(pd, 32);
            if (lane < 16) {
                const int n = n0 + wcl*64 + t*16 + lane;
                atomicAdd(&ssrc[(size_t)hdr*N_NODES + n], ps * LOG2E);
                atomicAdd(&sdst[(size_t)hdr*N_NODES + n], pd * LOG2E);
            }
        }
    }

#pragma unroll
    for (int r = 0; r < 4; ++r)
#pragma unroll
        for (int t = 0; t < 4; ++t)
#pragma unroll
            for (int g = 0; g < 4; ++g) {
                const int row = m0 + wr*64 + r*16 + l4*4 + g;
                const int col = n0 + wcl*64 + t*16 + l15;
                if (col < N) {
                    float v = acc[r][t][g] + (bias ? bias[col] : 0.f);
                    if (outF) outF[(size_t)row*N + col] = v;
                    else {
                        ushort_t hv = f2bf(v);
                        outHi[(size_t)row*N + col] = hv;
                        if (outLo) outLo[(size_t)row*N + col] = f2bf(v - bf2f(hv));
                    }
                }
            }
}

// ----------- maxsd[h] = max_j sdl[h][j]  (unmasked upper bound) -------------
__global__ __launch_bounds__(256)
void maxsd_kernel(const float* __restrict__ sdl, float* __restrict__ maxsd)
{
    const int h   = blockIdx.x;
    const int tid = threadIdx.x;
    const float* p = sdl + (size_t)h * N_NODES;
    float m = -INFINITY;
#pragma unroll
    for (int k = 0; k < 4; ++k) {
        float4 v = *(const float4*)(p + (k*256 + tid)*4);
        m = fmaxf(m, fmaxf(fmaxf(v.x, v.y), fmaxf(v.z, v.w)));
    }
#pragma unroll
    for (int off = 32; off; off >>= 1) m = fmaxf(m, __shfl_down(m, off));
    __shared__ float wm[4];
    if ((tid & 63) == 0) wm[tid >> 6] = m;
    __syncthreads();
    if (tid == 0)
        maxsd[h] = fmaxf(fmaxf(wm[0], wm[1]), fmaxf(wm[2], wm[3]));
}

// -------- attg: part[i][c] = sum_j P~(i,j) g[j][c];  zp[i] = sum_j P~(i,j) --
// P~ = 2^(max(t,.2t) - M_i) folded as 2^max(sslp+sd, sslq+.2sd); mask -> -inf
// pre-exp (exp2(-inf)=+0). 256 thr / 4 waves; tile 128 i x 128 c; wave 32i.
__global__ __launch_bounds__(256)
void attg_kernel(const ushort_t* __restrict__ gThi, const unsigned* __restrict__ maskJ,
                 const float* __restrict__ ssl, const float* __restrict__ maxsd,
                 const float* __restrict__ sdl, float* __restrict__ part0,
                 float* __restrict__ part1, float* __restrict__ zp)
{
    __shared__ ushort_t gsT[2][128*32];
    const int tid = threadIdx.x;
    const int w   = tid >> 6, lane = tid & 63;
    const int l15 = lane & 15, l4 = lane >> 4;
    const int h   = blockIdx.y >> 1;
    const int cs0 = (blockIdx.y & 1) * 128;
    const int i0  = blockIdx.x * 128;
    const int z   = blockIdx.z;
    const int jbase = z * (N_NODES/2);
    const size_t hN = (size_t)h * N_NODES;

    const int r0 = i0 + w*32 + l15;
    const int r1 = r0 + 16;
    const float msd  = maxsd[h];
    const float ssl0 = ssl[hN + r0], ssl1 = ssl[hN + r1];
    const float u0 = ssl0 + msd, u1 = ssl1 + msd;
    const float Cl0 = fmaxf(u0, ALPHA*u0);
    const float Cl1 = fmaxf(u1, ALPHA*u1);
    // folded row constants: exponent = max(sslp + sd, sslq + ALPHA*sd)
    const float sslp0 = ssl0 - Cl0, sslq0 = ALPHA*ssl0 - Cl0;
    const float sslp1 = ssl1 - Cl1, sslq1 = ALPHA*ssl1 - Cl1;

    f32x4 acc[2][8];
#pragma unroll
    for (int r = 0; r < 2; ++r)
#pragma unroll
        for (int t = 0; t < 8; ++t) acc[r][t] = (f32x4){0.f,0.f,0.f,0.f};
    f32x4 accz[2];
    accz[0] = (f32x4){0.f,0.f,0.f,0.f};
    accz[1] = (f32x4){0.f,0.f,0.f,0.f};
    bf16x8 ones;
#pragma unroll
    for (int q = 0; q < 8; ++q) ones[q] = (short)0x3F80;

    auto stage = [&](int buf, int j0){
#pragma unroll
        for (int s = 0; s < 2; ++s) {
            const int c    = w*32 + s*16 + (lane >> 2);
            const int slot = (lane & 3) ^ ((c >> 1) & 3);
            gload16(gThi + (size_t)(h*HID + cs0 + c)*N_NODES + j0 + slot*8,
                    &gsT[buf][(w*32 + s*16)*32]);
        }
    };

    stage(0, jbase);
    unsigned mwA = maskJ[(size_t)r0*NWORDS + (jbase>>5)];
    unsigned mwB = maskJ[(size_t)r1*NWORDS + (jbase>>5)];
    float4 sdA = *(const float4*)(sdl + hN + jbase + l4*8);
    float4 sdB = *(const float4*)(sdl + hN + jbase + l4*8 + 4);

    int buf = 0;
    for (int tt = 0; tt < 64; ++tt) {
        const int j0 = jbase + tt*32;
        __syncthreads();
        unsigned nmwA = 0, nmwB = 0; float4 nsdA = sdA, nsdB = sdB;
        if (tt + 1 < 64) {
            stage(buf^1, j0 + 32);
            nmwA = maskJ[(size_t)r0*NWORDS + ((j0+32)>>5)];
            nmwB = maskJ[(size_t)r1*NWORDS + ((j0+32)>>5)];
            nsdA = *(const float4*)(sdl + hN + j0 + 32 + l4*8);
            nsdB = *(const float4*)(sdl + hN + j0 + 32 + l4*8 + 4);
        }

        const float sdv[8] = {sdA.x,sdA.y,sdA.z,sdA.w,sdB.x,sdB.y,sdB.z,sdB.w};
        const unsigned ms0 = mwA >> (l4*8);
        const unsigned ms1 = mwB >> (l4*8);
        float p0v[8], p1v[8];
#pragma unroll
        for (int q = 0; q < 8; ++q) {
            const float sd  = sdv[q];
            const float sda = ALPHA * sd;                 // shared by both rows
            float t0 = fmaxf(sslp0 + sd, sslq0 + sda);
            float t1 = fmaxf(sslp1 + sd, sslq1 + sda);
            t0 = ((ms0 >> q) & 1u) ? t0 : -INFINITY;      // mask pre-exp
            t1 = ((ms1 >> q) & 1u) ? t1 : -INFINITY;
            p0v[q] = fexp2(t0);                           // exp2(-inf) = +0
            p1v[q] = fexp2(t1);
        }
        bf16x8 af0, af1;
#pragma unroll
        for (int q = 0; q < 8; ++q) {                     // adjacent casts fuse to cvt_pk
            af0[q] = (short)f2bf(p0v[q]);
            af1[q] = (short)f2bf(p1v[q]);
        }
#pragma unroll
        for (int t = 0; t < 8; ++t) {
            const int cloc = t*16 + l15;
            const int slot = l4 ^ ((cloc >> 1) & 3);
            const bf16x8 bfr = *(const bf16x8*)&gsT[buf][cloc*32 + slot*8];
            acc[0][t] = __builtin_amdgcn_mfma_f32_16x16x32_bf16(af0, bfr, acc[0][t], 0,0,0);
            acc[1][t] = __builtin_amdgcn_mfma_f32_16x16x32_bf16(af1, bfr, acc[1][t], 0,0,0);
        }
        if (cs0 == 0) {   // z row-sums needed once per (h,i,z): only cs0==0 blocks
            accz[0] = __builtin_amdgcn_mfma_f32_16x16x32_bf16(af0, ones, accz[0], 0,0,0);
            accz[1] = __builtin_amdgcn_mfma_f32_16x16x32_bf16(af1, ones, accz[1], 0,0,0);
        }
        mwA = nmwA; mwB = nmwB; sdA = nsdA; sdB = nsdB;
        buf ^= 1;
    }

    float* dst = z ? part1 : part0;
#pragma unroll
    for (int r = 0; r < 2; ++r)
#pragma unroll
        for (int t = 0; t < 8; ++t)
#pragma unroll
            for (int g = 0; g < 4; ++g) {
                const int row = i0 + w*32 + r*16 + l4*4 + g;
                const int col = h*HID + cs0 + t*16 + l15;
                dst[(size_t)row*GCOLS + col] = acc[r][t][g];
            }
    if (cs0 == 0 && l15 == 0) {
        float* zrow = zp + (size_t)(h*2 + z)*N_NODES + i0 + w*32;
#pragma unroll
        for (int r = 0; r < 2; ++r)
#pragma unroll
            for (int g = 0; g < 4; ++g)
                zrow[r*16 + l4*4 + g] = accz[r][g];
    }
}

// ---------- hcat (hi/lo bf16) = elu((part0+part1)/Z) ------------------------
__global__ __launch_bounds__(256)
void reduce_elu2(const float* __restrict__ p0, const float* __restrict__ p1,
                 const float* __restrict__ zp,
                 ushort_t* __restrict__ hi, ushort_t* __restrict__ lo)
{
    const int gid = blockIdx.x*256 + threadIdx.x;   // one float4
    const int row = gid >> 8;                        // GCOLS/4 = 256 groups/row
    const int c4  = (gid & 255) * 4;
    const int h   = c4 >> 8;
    const float zt = zp[(size_t)(h*2  )*N_NODES + row]
                   + zp[(size_t)(h*2+1)*N_NODES + row];
    const float inv = 1.f / zt;
    const size_t idx = (size_t)row*GCOLS + c4;
    float4 a = *(const float4*)(p0 + idx);
    float4 b = *(const float4*)(p1 + idx);
    float v0 = elu_f((a.x + b.x)*inv), v1 = elu_f((a.y + b.y)*inv);
    float v2 = elu_f((a.z + b.z)*inv), v3 = elu_f((a.w + b.w)*inv);
    ushort4 hh, ll;
    hh.x = f2bf(v0); ll.x = f2bf(v0 - bf2f(hh.x));
    hh.y = f2bf(v1); ll.y = f2bf(v1 - bf2f(hh.y));
    hh.z = f2bf(v2); ll.z = f2bf(v2 - bf2f(hh.z));
    hh.w = f2bf(v3); ll.w = f2bf(v3 - bf2f(hh.w));
    *(ushort4*)(hi + idx) = hh;
    *(ushort4*)(lo + idx) = ll;
}

extern "C" void kernel_launch(void* const* d_in, const int* in_sizes, int n_in,
                              void* d_out, int out_size, void* d_ws, size_t ws_size,
                              hipStream_t stream)
{
    const float* label = (const float*)d_in[0];
    const float* W1    = (const float*)d_in[1];
    const float* a1    = (const float*)d_in[2];
    const float* W2    = (const float*)d_in[3];
    const float* a2    = (const float*)d_in[4];
    const float* out_w = (const float*)d_in[5];
    const float* out_b = (const float*)d_in[6];
    const float* out2_w= (const float*)d_in[7];
    const float* out2_b= (const float*)d_in[8];
    const int*   adj   = (const int*)d_in[9];
    float* out = (float*)d_out;

    char* p = (char*)d_ws;
    auto alloc = [&](size_t bytes){ char* r = p; p += (bytes + 255) & ~(size_t)255; return r; };
    float*    part0 = (float*)   alloc((size_t)N_NODES*GCOLS*4);      // 16 MB
    float*    part1 = (float*)   alloc((size_t)N_NODES*GCOLS*4);      // 16 MB
    ushort_t* gThi  = (ushort_t*)alloc((size_t)GCOLS*N_NODES*2);      // 8 MB
    ushort_t* hchi  = (ushort_t*)alloc((size_t)N_NODES*GCOLS*2);      // 8 MB
    ushort_t* hclo  = (ushort_t*)alloc((size_t)N_NODES*GCOLS*2);      // 8 MB
    ushort_t* xlhi  = (ushort_t*)alloc((size_t)N_NODES*IN_DIM*2);     // 6 MB (label, then x1)
    ushort_t* xllo  = (ushort_t*)alloc((size_t)N_NODES*IN_DIM*2);     // 6 MB
    ushort_t* w1hi  = (ushort_t*)alloc((size_t)GCOLS*IN_DIM*2);
    ushort_t* w1lo  = (ushort_t*)alloc((size_t)GCOLS*IN_DIM*2);
    ushort_t* w2hi  = (ushort_t*)alloc((size_t)GCOLS*IN_DIM*2);
    ushort_t* w2lo  = (ushort_t*)alloc((size_t)GCOLS*IN_DIM*2);
    ushort_t* owhi  = (ushort_t*)alloc((size_t)IN_DIM*GCOLS*2);
    ushort_t* owlo  = (ushort_t*)alloc((size_t)IN_DIM*GCOLS*2);
    ushort_t* o2hi  = (ushort_t*)alloc((size_t)OUT_DIM*GCOLS*2);
    ushort_t* o2lo  = (ushort_t*)alloc((size_t)OUT_DIM*GCOLS*2);
    unsigned* maskJ = (unsigned*)alloc((size_t)N_NODES*NWORDS*4);     // 2 MB
    float*    ssrc  = (float*)   alloc((size_t)HEADS*N_NODES*4);
    float*    sdst  = (float*)   alloc((size_t)HEADS*N_NODES*4);
    float*    zbuf  = (float*)   alloc((size_t)HEADS*2*N_NODES*4);
    float*    msd   = (float*)   alloc(256);

    pack_kernel<<<N_NODES/4, 256, 0, stream>>>(adj, maskJ);
    cvt_hilo<<<(N_NODES*IN_DIM)/1024, 256, 0, stream>>>(label, xlhi, xllo, N_NODES*IN_DIM);
    cvt_hilo<<<(GCOLS*IN_DIM)/1024, 256, 0, stream>>>(W1, w1hi, w1lo, GCOLS*IN_DIM);
    cvt_hilo<<<(GCOLS*IN_DIM)/1024, 256, 0, stream>>>(W2, w2hi, w2lo, GCOLS*IN_DIM);
    cvt_hilo<<<(IN_DIM*GCOLS)/1024, 256, 0, stream>>>(out_w, owhi, owlo, IN_DIM*GCOLS);
    cvt_hilo<<<(OUT_DIM*GCOLS)/1024, 256, 0, stream>>>(out2_w, o2hi, o2lo, OUT_DIM*GCOLS);

    auto layer = [&](const ushort_t* Whi, const ushort_t* Wlo, const float* avec,
                     const ushort_t* hhi, const ushort_t* hlo, int K) {
        zero_kernel<<<(2*HEADS*N_NODES)/256, 256, 0, stream>>>(ssrc, 2*HEADS*N_NODES);
        // gT[c][j] (+ scaled s_src/s_dst atomics):  gT = W @ h^T
        gemm_hilo<<<dim3(N_NODES/128, GCOLS/128), 256, 0, stream>>>(
            Whi, Wlo, hhi, hlo, nullptr, nullptr, gThi, nullptr,
            avec, ssrc, sdst, GCOLS, N_NODES, K);
        maxsd_kernel<<<HEADS, 256, 0, stream>>>(sdst, msd);
        attg_kernel<<<dim3(N_NODES/128, HEADS*2, 2), 256, 0, stream>>>(
            gThi, maskJ, ssrc, msd, sdst, part0, part1, zbuf);
        reduce_elu2<<<(N_NODES*GCOLS)/1024, 256, 0, stream>>>(part0, part1, zbuf, hchi, hclo);
    };

    layer(w1hi, w1lo, a1, xlhi, xllo, IN_DIM);
    // x1 = hcat @ out_w^T + out_b  -> split bf16 (overwrites label slot)
    gemm_hilo<<<dim3(IN_DIM/128, N_NODES/128), 256, 0, stream>>>(
        hchi, hclo, owhi, owlo, out_b, nullptr, xlhi, xllo,
        nullptr, nullptr, nullptr, N_NODES, IN_DIM, GCOLS);
    layer(w2hi, w2lo, a2, xlhi, xllo, IN_DIM);
    // out = hcat @ out2_w^T + out2_b  (fp32, N=32 guarded)
    gemm_hilo<<<dim3(1, N_NODES/128), 256, 0, stream>>>(
        hchi, hclo, o2hi, o2lo, out2_b, out, nullptr, nullptr,
        nullptr, nullptr, nullptr, N_NODES, OUT_DIM, GCOLS);
}